// Round 4
// baseline (803.967 us; speedup 1.0000x reference)
//
#include <hip/hip_runtime.h>
#include <math.h>
#include <stdint.h>

#define M_NODES 8192
#define E_DIM   512
#define NTOPK   6
#define ATTN_SCALE 0.04419417382415922f  // 512^-0.5
#define NEG_BIG (-1e38f)
#define BAND    1024

typedef __attribute__((ext_vector_type(8))) short short8;
typedef __attribute__((ext_vector_type(4))) float f32x4;

__device__ __forceinline__ float lrelu(float v) { return v > 0.f ? v : 0.01f * v; }

__device__ __forceinline__ unsigned short f2bf(float f) {
  uint32_t u = __float_as_uint(f);
  uint32_t r = (u + 0x7FFFu + ((u >> 16) & 1u)) >> 16;
  return (unsigned short)r;
}
__device__ __forceinline__ float bf2f(unsigned short s) {
  return __uint_as_float(((uint32_t)s) << 16);
}

// async 16B/lane global->LDS (wave-uniform LDS base, lane i lands at base+16i)
__device__ __forceinline__ void async_cp16(const void* gptr, void* lds) {
  auto g1 = reinterpret_cast<const __attribute__((address_space(1))) unsigned int*>(
      reinterpret_cast<uintptr_t>(gptr));
  auto l3 = reinterpret_cast<__attribute__((address_space(3))) unsigned int*>(
      reinterpret_cast<uintptr_t>(lds));
  __builtin_amdgcn_global_load_lds(g1, l3, 16, 0, 0);
}

// tiled bf16 layout: value (m,k), Ktiles=K/32:
//   idx = ((m>>4)*Ktiles + (k>>5))*512 + ((m&15) + 16*((k>>3)&3))*8 + (k&7)

// ---------------------------------------------------------------------------
// Cast fp32 x + 6 weight matrices into bf16 frag-tiled layout.
// ---------------------------------------------------------------------------
__global__ __launch_bounds__(256) void wcast_kernel(
    const float* __restrict__ x, const float* __restrict__ fc1w,
    const float* __restrict__ whw, const float* __restrict__ wtw,
    const float* __restrict__ l1w, const float* __restrict__ l2w,
    const float* __restrict__ a1w,
    unsigned short* __restrict__ xT, unsigned short* __restrict__ fc1T,
    unsigned short* __restrict__ whT, unsigned short* __restrict__ wtT,
    unsigned short* __restrict__ l1T, unsigned short* __restrict__ l2T,
    unsigned short* __restrict__ a1T)
{
  const int gid = blockIdx.x * 256 + threadIdx.x;  // 0 .. 565247
  const float* src; unsigned short* dst; int K8, local;
  if (gid < 417792) {
    K8 = 48;
    if (gid < 393216) { src = x; dst = xT; local = gid; }
    else { src = fc1w; dst = fc1T; local = gid - 393216; }
  } else {
    K8 = 64;
    if (gid < 450560)      { src = whw; dst = whT; local = gid - 417792; }
    else if (gid < 483328) { src = wtw; dst = wtT; local = gid - 450560; }
    else if (gid < 516096) { src = l1w; dst = l1T; local = gid - 483328; }
    else if (gid < 548864) { src = l2w; dst = l2T; local = gid - 516096; }
    else                   { src = a1w; dst = a1T; local = gid - 548864; }
  }
  const int m = local / K8;
  const int k8 = local - m * K8;
  const float* p = src + (size_t)m * (K8 * 8) + k8 * 8;
  float4 v0 = ((const float4*)p)[0];
  float4 v1 = ((const float4*)p)[1];
  const int Kt = K8 >> 2;
  const size_t ti = ((size_t)(m >> 4) * Kt + (k8 >> 2)) * 512 + ((m & 15) + 16 * (k8 & 3)) * 8;
  uint4 pk;
  pk.x = (uint32_t)f2bf(v0.x) | ((uint32_t)f2bf(v0.y) << 16);
  pk.y = (uint32_t)f2bf(v0.z) | ((uint32_t)f2bf(v0.w) << 16);
  pk.z = (uint32_t)f2bf(v1.x) | ((uint32_t)f2bf(v1.y) << 16);
  pk.w = (uint32_t)f2bf(v1.z) | ((uint32_t)f2bf(v1.w) << 16);
  *(uint4*)(dst + ti) = pk;
}

// ---------------------------------------------------------------------------
// MFMA GEMM, tile 128(M) x 64(N), 4 waves each 32x64, K-step 32.
// MODE 0: Cf fp32 = lrelu(A@W1^T + b1)
// MODE 1: T1 = bf16(A@W1^T+b1) tiled ; T2 = bf16(A@W2^T+b2) tiled  (no fp32 out)
// MODE 2: e = lrelu(A1@W1^T+b1)+lrelu(A2@W2^T+b2) ; T1 = bf16(e) tiled ;
//         Cbf = bf16(e) row-major
// ---------------------------------------------------------------------------
template <int MODE>
__global__ __launch_bounds__(256) void mfma_gemm(
    const unsigned short* __restrict__ At1, const unsigned short* __restrict__ At2,
    const unsigned short* __restrict__ Wt1, const unsigned short* __restrict__ Wt2,
    const float* __restrict__ b1, const float* __restrict__ b2,
    float* __restrict__ Cf, unsigned short* __restrict__ T1,
    unsigned short* __restrict__ T2, unsigned short* __restrict__ Cbf,
    int N, int K)
{
  __shared__ unsigned short As[2][8 * 512];
  __shared__ unsigned short Bs[2][4 * 512];
  const int Kt = K >> 5;
  const int tid = threadIdx.x, lane = tid & 63, w = tid >> 6;
  const int m0 = blockIdx.y * 128, n0 = blockIdx.x * 64;

  f32x4 acc0[2][4], acc1[2][4];
#pragma unroll
  for (int p = 0; p < 2; p++)
#pragma unroll
    for (int j = 0; j < 4; j++) {
      acc0[p][j] = (f32x4){0.f, 0.f, 0.f, 0.f};
      acc1[p][j] = (f32x4){0.f, 0.f, 0.f, 0.f};
    }

  for (int kt = 0; kt < Kt; kt++) {
    const unsigned short* a1p = At1 + ((size_t)((m0 >> 4) + 2 * w) * Kt + kt) * 512 + lane * 8;
    async_cp16(a1p, &As[0][(2 * w) * 512]);
    async_cp16(a1p + (size_t)Kt * 512, &As[0][(2 * w + 1) * 512]);
    if (MODE == 2) {
      const unsigned short* a2p = At2 + ((size_t)((m0 >> 4) + 2 * w) * Kt + kt) * 512 + lane * 8;
      async_cp16(a2p, &As[1][(2 * w) * 512]);
      async_cp16(a2p + (size_t)Kt * 512, &As[1][(2 * w + 1) * 512]);
    }
    const unsigned short* bp1 = Wt1 + ((size_t)((n0 >> 4) + w) * Kt + kt) * 512 + lane * 8;
    async_cp16(bp1, &Bs[0][w * 512]);
    if (MODE >= 1) {
      const unsigned short* bp2 = Wt2 + ((size_t)((n0 >> 4) + w) * Kt + kt) * 512 + lane * 8;
      async_cp16(bp2, &Bs[1][w * 512]);
    }
    __syncthreads();
    short8 a[2], a2[2], bb[4], bb2[4];
#pragma unroll
    for (int p = 0; p < 2; p++) a[p] = *(const short8*)&As[0][(2 * w + p) * 512 + lane * 8];
    if (MODE == 2) {
#pragma unroll
      for (int p = 0; p < 2; p++) a2[p] = *(const short8*)&As[1][(2 * w + p) * 512 + lane * 8];
    }
#pragma unroll
    for (int j = 0; j < 4; j++) bb[j] = *(const short8*)&Bs[0][j * 512 + lane * 8];
    if (MODE >= 1) {
#pragma unroll
      for (int j = 0; j < 4; j++) bb2[j] = *(const short8*)&Bs[1][j * 512 + lane * 8];
    }
#pragma unroll
    for (int p = 0; p < 2; p++)
#pragma unroll
      for (int j = 0; j < 4; j++) {
        acc0[p][j] = __builtin_amdgcn_mfma_f32_16x16x32_bf16(a[p], bb[j], acc0[p][j], 0, 0, 0);
        if (MODE == 1)
          acc1[p][j] = __builtin_amdgcn_mfma_f32_16x16x32_bf16(a[p], bb2[j], acc1[p][j], 0, 0, 0);
        if (MODE == 2)
          acc1[p][j] = __builtin_amdgcn_mfma_f32_16x16x32_bf16(a2[p], bb2[j], acc1[p][j], 0, 0, 0);
      }
    __syncthreads();
  }

  const int lrow = (lane >> 4) * 4, lcol = lane & 15;
  const int NT = N >> 5;
#pragma unroll
  for (int p = 0; p < 2; p++)
#pragma unroll
    for (int j = 0; j < 4; j++) {
      const int c = n0 + j * 16 + lcol;
      const float bias1 = b1[c];
      const float bias2 = (MODE >= 1) ? b2[c] : 0.f;
#pragma unroll
      for (int d = 0; d < 4; d++) {
        const int r = m0 + w * 32 + p * 16 + lrow + d;
        const float v0 = acc0[p][j][d] + bias1;
        if (MODE == 0) {
          Cf[(size_t)r * N + c] = lrelu(v0);
        } else {
          const size_t ti = ((size_t)(r >> 4) * NT + (c >> 5)) * 512 +
                            ((r & 15) + 16 * ((c >> 3) & 3)) * 8 + (c & 7);
          if (MODE == 1) {
            T1[ti] = f2bf(v0);
            T2[ti] = f2bf(acc1[p][j][d] + bias2);
          } else {
            const float e = lrelu(v0) + lrelu(acc1[p][j][d] + bias2);
            T1[ti] = f2bf(e);
            Cbf[(size_t)r * N + c] = f2bf(e);
          }
        }
      }
    }
}

// ---------------------------------------------------------------------------
// Column sum of h over M
// ---------------------------------------------------------------------------
__global__ __launch_bounds__(256) void colsum_kernel(const float* __restrict__ h,
                                                     float* __restrict__ colsum)
{
  const int t = threadIdx.x;
  const int r0 = blockIdx.x * 128;
  float s0 = 0.f, s1 = 0.f;
  for (int r = 0; r < 128; r++) {
    s0 += h[(size_t)(r0 + r) * E_DIM + t];
    s1 += h[(size_t)(r0 + r) * E_DIM + 256 + t];
  }
  atomicAdd(&colsum[t], s0);
  atomicAdd(&colsum[t + 256], s1);
}

// h' = (h + colmean)*0.5 fused with bf16 tiled cast (Ktiles=16)
__global__ __launch_bounds__(256) void hupd_cast_kernel(
    const float* __restrict__ h, const float* __restrict__ colsum,
    unsigned short* __restrict__ hT)
{
  const int gid = blockIdx.x * 256 + threadIdx.x;  // 8192*64
  const int m = gid >> 6, k8 = gid & 63;
  const float* p = h + (size_t)m * E_DIM + k8 * 8;
  float4 v0 = ((const float4*)p)[0];
  float4 v1 = ((const float4*)p)[1];
  float4 c0 = *(const float4*)(colsum + k8 * 8);
  float4 c1 = *(const float4*)(colsum + k8 * 8 + 4);
  const float im = 1.f / (float)M_NODES;
  v0.x = (v0.x + c0.x * im) * 0.5f; v0.y = (v0.y + c0.y * im) * 0.5f;
  v0.z = (v0.z + c0.z * im) * 0.5f; v0.w = (v0.w + c0.w * im) * 0.5f;
  v1.x = (v1.x + c1.x * im) * 0.5f; v1.y = (v1.y + c1.y * im) * 0.5f;
  v1.z = (v1.z + c1.z * im) * 0.5f; v1.w = (v1.w + c1.w * im) * 0.5f;
  const size_t ti = ((size_t)(m >> 4) * 16 + (k8 >> 2)) * 512 + ((m & 15) + 16 * (k8 & 3)) * 8;
  uint4 pk;
  pk.x = (uint32_t)f2bf(v0.x) | ((uint32_t)f2bf(v0.y) << 16);
  pk.y = (uint32_t)f2bf(v0.z) | ((uint32_t)f2bf(v0.w) << 16);
  pk.z = (uint32_t)f2bf(v1.x) | ((uint32_t)f2bf(v1.y) << 16);
  pk.w = (uint32_t)f2bf(v1.z) | ((uint32_t)f2bf(v1.w) << 16);
  *(uint4*)(hT + ti) = pk;
}

// ---------------------------------------------------------------------------
// Score GEMM (one band of 1024 rows): sc[band_row][8192] = bf16(eh . et)
// 128x128 tile, 4 waves each 64x64, BK=32, m97-style 2-barrier K-loop.
// ---------------------------------------------------------------------------
__global__ __launch_bounds__(256) void sgemm_kernel(
    const unsigned short* __restrict__ ehT, const unsigned short* __restrict__ etT,
    unsigned short* __restrict__ sc, int mbase)
{
  __shared__ unsigned short As[8 * 512];
  __shared__ unsigned short Bs[8 * 512];
  __shared__ unsigned short Sc[128 * 136];
  const int tid = threadIdx.x, lane = tid & 63, w = tid >> 6;
  const int wr = w >> 1, wc = w & 1;
  const int m0 = mbase + blockIdx.y * 128;
  const int n0 = blockIdx.x * 128;

  f32x4 acc[4][4];
#pragma unroll
  for (int i = 0; i < 4; i++)
#pragma unroll
    for (int j = 0; j < 4; j++) acc[i][j] = (f32x4){0.f, 0.f, 0.f, 0.f};

  for (int kt = 0; kt < 16; kt++) {
    const int s0 = w, s1 = w + 4;
    async_cp16(ehT + ((size_t)((m0 >> 4) + s0) * 16 + kt) * 512 + lane * 8, &As[s0 * 512]);
    async_cp16(ehT + ((size_t)((m0 >> 4) + s1) * 16 + kt) * 512 + lane * 8, &As[s1 * 512]);
    async_cp16(etT + ((size_t)((n0 >> 4) + s0) * 16 + kt) * 512 + lane * 8, &Bs[s0 * 512]);
    async_cp16(etT + ((size_t)((n0 >> 4) + s1) * 16 + kt) * 512 + lane * 8, &Bs[s1 * 512]);
    __syncthreads();
    short8 a[4], b[4];
#pragma unroll
    for (int i = 0; i < 4; i++) a[i] = *(const short8*)&As[(wr * 4 + i) * 512 + lane * 8];
#pragma unroll
    for (int j = 0; j < 4; j++) b[j] = *(const short8*)&Bs[(wc * 4 + j) * 512 + lane * 8];
#pragma unroll
    for (int i = 0; i < 4; i++)
#pragma unroll
      for (int j = 0; j < 4; j++)
        acc[i][j] = __builtin_amdgcn_mfma_f32_16x16x32_bf16(a[i], b[j], acc[i][j], 0, 0, 0);
    __syncthreads();
  }

  // frags -> LDS bf16 (C layout: col=lane&15, row=quad*4+reg)
  const int lrow = (lane >> 4) * 4, lcol = lane & 15;
#pragma unroll
  for (int i = 0; i < 4; i++) {
    const int row = wr * 64 + i * 16 + lrow;
#pragma unroll
    for (int j = 0; j < 4; j++) {
      const int col = wc * 64 + j * 16 + lcol;
      Sc[(row + 0) * 136 + col] = f2bf(acc[i][j][0]);
      Sc[(row + 1) * 136 + col] = f2bf(acc[i][j][1]);
      Sc[(row + 2) * 136 + col] = f2bf(acc[i][j][2]);
      Sc[(row + 3) * 136 + col] = f2bf(acc[i][j][3]);
    }
  }
  __syncthreads();

  // coalesced store: thread t -> row t>>1, 64-col half t&1
  const int row = tid >> 1, half = tid & 1;
  const unsigned short* src = &Sc[row * 136 + half * 64];
  unsigned short* dst = sc + (size_t)(m0 - mbase + row) * M_NODES + n0 + half * 64;
#pragma unroll
  for (int q = 0; q < 8; q++)
    *(short8*)(dst + q * 8) = *(const short8*)(src + q * 8);
}

// ---------------------------------------------------------------------------
// Exact top-6 scan, one row per wave, ballot-gated wave-uniform inserts.
// grid 256 x 256thr (4 waves) = 1024 rows = one band.
// ---------------------------------------------------------------------------
__global__ __launch_bounds__(256) void scan_topk_kernel(
    const unsigned short* __restrict__ sc, int mbase,
    float* __restrict__ tkv, int* __restrict__ tki)
{
  const int lane = threadIdx.x & 63;
  const int row = blockIdx.x * 4 + (threadIdx.x >> 6);
  const unsigned short* rp = sc + (size_t)row * M_NODES;

  float v[NTOPK]; int id[NTOPK];
#pragma unroll
  for (int k = 0; k < NTOPK; k++) { v[k] = NEG_BIG; id[k] = 0; }
  float cmin = NEG_BIG;

  for (int b = 0; b < 16; b++) {
    short8 u = *(const short8*)(rp + b * 512 + lane * 8);
    float f[8];
#pragma unroll
    for (int e = 0; e < 8; e++) f[e] = bf2f((unsigned short)u[e]);
    float m8 = fmaxf(fmaxf(fmaxf(f[0], f[1]), fmaxf(f[2], f[3])),
                     fmaxf(fmaxf(f[4], f[5]), fmaxf(f[6], f[7])));
    unsigned long long mask = __ballot(m8 > cmin);
    while (mask) {
      const int l = __ffsll(mask) - 1;
      mask &= mask - 1;
#pragma unroll
      for (int e = 0; e < 8; e++) {
        const float x = __shfl(f[e], l);
        if (x > cmin) {
          // sorted insert (descending), stable on ties (earlier idx stays)
          float nv = x; int ni = b * 512 + l * 8 + e;
#pragma unroll
          for (int k = 0; k < NTOPK; k++) {
            const bool gt = nv > v[k];
            const float tv = v[k]; const int tid2 = id[k];
            v[k] = gt ? nv : tv; id[k] = gt ? ni : tid2;
            nv = gt ? tv : nv;   ni = gt ? tid2 : ni;
          }
          cmin = v[NTOPK - 1];
        }
      }
    }
  }
  if (lane == 0) {
    const size_t base = (size_t)(mbase + row) * NTOPK;
#pragma unroll
    for (int k = 0; k < NTOPK; k++) {
      tkv[base + k] = v[k] * ATTN_SCALE;
      tki[base + k] = id[k];
    }
  }
}

// ---------------------------------------------------------------------------
// Per-row combine: softmax over top-6, gather Nb from etT (bf16 tiled),
// gate tanh, ka softmax, e_Nh; write s1=eh+eNh, s2=eh*eNh bf16 tiled.
// One wave per row. e_h read from ehT (bf16 tiled, unscaled).
// ---------------------------------------------------------------------------
__global__ __launch_bounds__(256) void combine_kernel(
    const unsigned short* __restrict__ ehT, const unsigned short* __restrict__ etT,
    const float* __restrict__ tkv, const int* __restrict__ tki,
    unsigned short* __restrict__ s1T, unsigned short* __restrict__ s2T)
{
  const int lane = threadIdx.x & 63;
  const int m = blockIdx.x * 4 + (threadIdx.x >> 6);

  float wv[NTOPK]; int id[NTOPK];
#pragma unroll
  for (int k = 0; k < NTOPK; k++) {
    wv[k] = tkv[(size_t)m * NTOPK + k];
    id[k] = tki[(size_t)m * NTOPK + k];
  }

  float mx = wv[0];
#pragma unroll
  for (int k = 1; k < NTOPK; k++) mx = fmaxf(mx, wv[k]);
  float p[NTOPK]; float s = 0.f;
#pragma unroll
  for (int k = 0; k < NTOPK; k++) { p[k] = expf(wv[k] - mx); s += p[k]; }
  const float inv = 1.f / s;
#pragma unroll
  for (int k = 0; k < NTOPK; k++) p[k] *= inv;

  // tiled per-lane addressing: k-dim index = lane + 64*i
  const int wconst_base = 16 * ((lane >> 3) & 3) * 8 + (lane & 7);
  const unsigned short* ep = ehT + ((size_t)(m >> 4) * 16 + (lane >> 5)) * 512 +
                             (m & 15) * 8 + wconst_base;
  float ehv[8];
#pragma unroll
  for (int i = 0; i < 8; i++) ehv[i] = bf2f(ep[i * 1024]);

  float nv[NTOPK][8];
#pragma unroll
  for (int k = 0; k < NTOPK; k++) {
    const int n = id[k];
    const unsigned short* bp = etT + ((size_t)(n >> 4) * 16 + (lane >> 5)) * 512 +
                               (n & 15) * 8 + wconst_base;
#pragma unroll
    for (int i = 0; i < 8; i++) nv[k][i] = bf2f(bp[i * 1024]);
  }

  float ka[NTOPK];
#pragma unroll
  for (int k = 0; k < NTOPK; k++) {
    float snb = 0.f, sg = 0.f;
    const float aa = 2.f - p[k], bb = p[k];
#pragma unroll
    for (int i = 0; i < 8; i++) {
      snb += nv[k][i];
      sg += tanhf(fmaf(aa, ehv[i], bb * nv[k][i]));
    }
#pragma unroll
    for (int off = 32; off; off >>= 1) {
      snb += __shfl_xor(snb, off);
      sg += __shfl_xor(sg, off);
    }
    ka[k] = snb * sg;
  }
  float km = ka[0];
#pragma unroll
  for (int k = 1; k < NTOPK; k++) km = fmaxf(km, ka[k]);
  float kp[NTOPK]; float ks = 0.f;
#pragma unroll
  for (int k = 0; k < NTOPK; k++) { kp[k] = expf(ka[k] - km); ks += kp[k]; }
  const float kinv = 1.f / ks;

  unsigned short* o1 = s1T + ((size_t)(m >> 4) * 16 + (lane >> 5)) * 512 +
                       (m & 15) * 8 + wconst_base;
  unsigned short* o2 = s2T + ((size_t)(m >> 4) * 16 + (lane >> 5)) * 512 +
                       (m & 15) * 8 + wconst_base;
#pragma unroll
  for (int i = 0; i < 8; i++) {
    float o = 0.f;
#pragma unroll
    for (int k = 0; k < NTOPK; k++) o = fmaf(kp[k], nv[k][i], o);
    o *= kinv;
    o1[i * 1024] = f2bf(ehv[i] + o);
    o2[i * 1024] = f2bf(ehv[i] * o);
  }
}

// ---------------------------------------------------------------------------
__global__ __launch_bounds__(256) void gate_g_kernel(
    const float* __restrict__ ahid, const float* __restrict__ a2w,
    const float* __restrict__ a2b, float* __restrict__ g)
{
  const int lane = threadIdx.x & 63;
  const int m = blockIdx.x * 4 + (threadIdx.x >> 6);
  float s = 0.f;
  for (int j = lane; j < 256; j += 64)
    s = fmaf(a2w[j], ahid[(size_t)m * 256 + j], s);
#pragma unroll
  for (int off = 32; off; off >>= 1) s += __shfl_xor(s, off);
  if (lane == 0) g[m] = s + a2b[0];
}

__global__ __launch_bounds__(1024) void softmax_stats_kernel(
    const float* __restrict__ g, float* __restrict__ stats)
{
  __shared__ float red[16];
  __shared__ float red2[16];
  const int t = threadIdx.x;
  float mx = NEG_BIG;
  for (int i = t; i < M_NODES; i += 1024) mx = fmaxf(mx, g[i]);
#pragma unroll
  for (int off = 32; off; off >>= 1) mx = fmaxf(mx, __shfl_xor(mx, off));
  if ((t & 63) == 0) red[t >> 6] = mx;
  __syncthreads();
  float gmx = red[0];
  for (int i = 1; i < 16; i++) gmx = fmaxf(gmx, red[i]);
  float s = 0.f;
  for (int i = t; i < M_NODES; i += 1024) s += expf(g[i] - gmx);
#pragma unroll
  for (int off = 32; off; off >>= 1) s += __shfl_xor(s, off);
  if ((t & 63) == 0) red2[t >> 6] = s;
  __syncthreads();
  if (t == 0) {
    float tot = 0.f;
    for (int i = 0; i < 16; i++) tot += red2[i];
    stats[0] = gmx; stats[1] = tot;
  }
}

__global__ __launch_bounds__(256) void pooled_kernel(
    const unsigned short* __restrict__ emb, const float* __restrict__ g,
    const float* __restrict__ stats, float* __restrict__ pooled)
{
  const int t = threadIdx.x;
  const int r0 = blockIdx.x * 128;
  const float mx = stats[0];
  const float inv = 1.f / stats[1];
  float a0 = 0.f, a1 = 0.f;
  for (int r = 0; r < 128; r++) {
    const int m = r0 + r;
    const float wv = expf(g[m] - mx) * inv;
    a0 = fmaf(wv, bf2f(emb[(size_t)m * E_DIM + t]), a0);
    a1 = fmaf(wv, bf2f(emb[(size_t)m * E_DIM + 256 + t]), a1);
  }
  atomicAdd(&pooled[t], a0);
  atomicAdd(&pooled[t + 256], a1);
}

__global__ __launch_bounds__(512) void ln_kernel(
    const float* __restrict__ pooled, const float* __restrict__ lng,
    const float* __restrict__ lnb, float* __restrict__ out)
{
  __shared__ float red[8];
  __shared__ float red2[8];
  const int t = threadIdx.x;
  const float v = pooled[t];
  float s = v;
#pragma unroll
  for (int off = 32; off; off >>= 1) s += __shfl_xor(s, off);
  if ((t & 63) == 0) red[t >> 6] = s;
  __syncthreads();
  float tot = 0.f;
  for (int i = 0; i < 8; i++) tot += red[i];
  const float mu = tot / (float)E_DIM;
  const float d = v - mu;
  float q = d * d;
#pragma unroll
  for (int off = 32; off; off >>= 1) q += __shfl_xor(q, off);
  if ((t & 63) == 0) red2[t >> 6] = q;
  __syncthreads();
  float vt = 0.f;
  for (int i = 0; i < 8; i++) vt += red2[i];
  const float var = vt / (float)E_DIM;
  out[t] = d * rsqrtf(var + 1e-5f) * lng[t] + lnb[t];
}

// ---------------------------------------------------------------------------
extern "C" void kernel_launch(void* const* d_in, const int* in_sizes, int n_in,
                              void* d_out, int out_size, void* d_ws, size_t ws_size,
                              hipStream_t stream)
{
  const float* x     = (const float*)d_in[0];
  const float* fc1_w = (const float*)d_in[1];
  const float* fc1_b = (const float*)d_in[2];
  const float* wh_w  = (const float*)d_in[3];
  const float* wh_b  = (const float*)d_in[4];
  const float* wt_w  = (const float*)d_in[5];
  const float* wt_b  = (const float*)d_in[6];
  const float* l1_w  = (const float*)d_in[7];
  const float* l1_b  = (const float*)d_in[8];
  const float* l2_w  = (const float*)d_in[9];
  const float* l2_b  = (const float*)d_in[10];
  const float* a1_w  = (const float*)d_in[11];
  const float* a1_b  = (const float*)d_in[12];
  const float* a2_w  = (const float*)d_in[13];
  const float* a2_b  = (const float*)d_in[14];
  const float* ln_g  = (const float*)d_in[15];
  const float* ln_b  = (const float*)d_in[16];

  char* ws = (char*)d_ws;
  const size_t MiB = 1 << 20;
  // weight tiles [0, 2.75Mi) — live whole run
  unsigned short* fc1T = (unsigned short*)(ws + 0);
  unsigned short* whT  = (unsigned short*)(ws + 393216);
  unsigned short* wtT  = (unsigned short*)(ws + 917504);
  unsigned short* l1T  = (unsigned short*)(ws + 1441792);
  unsigned short* l2T  = (unsigned short*)(ws + 1966080);
  unsigned short* a1T  = (unsigned short*)(ws + 2490368);
  // activations (overlaid, liveness-checked):
  unsigned short* xT     = (unsigned short*)(ws + 3 * MiB);    // [3,9) wcast->gemm1
  float*          h      = (float*)(ws + 9 * MiB);             // [9,25) gemm1->hupd
  unsigned short* hT     = (unsigned short*)(ws + 25 * MiB);   // [25,33) hupd->gemm2
  unsigned short* ehT    = (unsigned short*)(ws + 3 * MiB);    // [3,11) gemm2->combine
  unsigned short* etT    = (unsigned short*)(ws + 11 * MiB);   // [11,19) gemm2->combine
  unsigned short* scores = (unsigned short*)(ws + 19 * MiB);   // [19,35) band (hT dead)
  unsigned short* s1T    = (unsigned short*)(ws + 19 * MiB);   // [19,27) combine->gemm3
  unsigned short* s2T    = (unsigned short*)(ws + 27 * MiB);   // [27,35) combine->gemm3
  unsigned short* embT   = (unsigned short*)(ws + 3 * MiB);    // [3,11) gemm3->gemm4
  unsigned short* embRow = (unsigned short*)(ws + 11 * MiB);   // [11,19) gemm3->pooled
  float*          ahid   = (float*)(ws + 19 * MiB);            // [19,27) gemm4->gate
  char*           smal   = ws + 37 * MiB;
  float* tkv    = (float*)(smal);                              // 196608 B
  int*   tki    = (int*)(smal + 196608);                       // 196608 B
  float* colsum = (float*)(smal + 393216);
  float* g      = (float*)(smal + 397312);
  float* stats  = (float*)(smal + 430080);
  float* pooled = (float*)(smal + 434176);

  hipMemsetAsync(smal + 393216, 0, 43008, stream);

  // 0. cast x + all weights to bf16 tiled
  wcast_kernel<<<2208, 256, 0, stream>>>(x, fc1_w, wh_w, wt_w, l1_w, l2_w, a1_w,
                                         xT, fc1T, whT, wtT, l1T, l2T, a1T);
  // 1. h = lrelu(x @ fc1^T + b)
  mfma_gemm<0><<<dim3(8, 64), 256, 0, stream>>>(
      xT, nullptr, fc1T, nullptr, fc1_b, nullptr, h, nullptr, nullptr, nullptr, 512, 384);
  // 2. colmean + mix + bf16 tiled cast
  colsum_kernel<<<64, 256, 0, stream>>>(h, colsum);
  hupd_cast_kernel<<<2048, 256, 0, stream>>>(h, colsum, hT);
  // 3. e_h, e_t (bf16 tiled, unscaled)
  mfma_gemm<1><<<dim3(8, 64), 256, 0, stream>>>(
      hT, nullptr, whT, wtT, wh_b, wt_b, nullptr, ehT, etT, nullptr, 512, 512);
  // 4. banded score GEMM + exact top-6 scan
  for (int band = 0; band < M_NODES / BAND; band++) {
    sgemm_kernel<<<dim3(64, BAND / 128), 256, 0, stream>>>(ehT, etT, scores, band * BAND);
    scan_topk_kernel<<<BAND / 4, 256, 0, stream>>>(scores, band * BAND, tkv, tki);
  }
  // 5. combine -> s1T, s2T (bf16 tiled)
  combine_kernel<<<M_NODES / 4, 256, 0, stream>>>(ehT, etT, tkv, tki, s1T, s2T);
  // 6. emb = lrelu(s1@l1^T+b1)+lrelu(s2@l2^T+b2) -> bf16 tiled + bf16 row
  mfma_gemm<2><<<dim3(8, 64), 256, 0, stream>>>(
      s1T, s2T, l1T, l2T, l1_b, l2_b, nullptr, embT, nullptr, embRow, 512, 512);
  // 7. ahid = lrelu(emb @ a1^T + b)  [8192x256]
  mfma_gemm<0><<<dim3(4, 64), 256, 0, stream>>>(
      embT, nullptr, a1T, nullptr, a1_b, nullptr, ahid, nullptr, nullptr, nullptr, 256, 512);
  // 8-11. readout
  gate_g_kernel<<<M_NODES / 4, 256, 0, stream>>>(ahid, a2_w, a2_b, g);
  softmax_stats_kernel<<<1, 1024, 0, stream>>>(g, stats);
  pooled_kernel<<<64, 256, 0, stream>>>(embRow, g, stats, pooled);
  ln_kernel<<<1, 512, 0, stream>>>(pooled, ln_g, ln_b, (float*)d_out);
}